// Round 3
// baseline (81.746 us; speedup 1.0000x reference)
//
#include <hip/hip_runtime.h>
#include <stdint.h>

#define H 512
#define W 512
#define B 8
#define TW 32
#define TILEH 32
#define NBX (W / TW)          // 16
#define NBY (H / TILEH)       // 16
#define NBLK (NBX * NBY * B)  // 2048

// Single fused kernel:
//  - edge bitmasks via wave ballot (40x40 halo window), target tile stashed in LDS
//  - clipped EDT from bitmasks: +/-oy rows folded (allow/d2 depend on |oy| only),
//    nearest-set-bit via brev/ffs, row masks hoisted per-thread (9 LDS b64 reads)
//  - softmax/CE/dice/argmax for 4 consecutive pixels per thread (float4 loads)
//  - ballot+popc for indicator sums, shuffle reduce, per-block partials
//  - last-block-done final reduction (counter zeroed by 4B memsetAsync per launch)
__global__ __launch_bounds__(256) void seg_fused(const float* __restrict__ preds,
                                                 const int* __restrict__ tgt,
                                                 float* __restrict__ partials,
                                                 unsigned int* __restrict__ counter,
                                                 float* __restrict__ out) {
    __shared__ unsigned long long emask[40];   // rows by0-4 .. by0+35; bit c <-> ex = bx0-4+c
    __shared__ unsigned char tileT[32][32];    // target classes of the owned tile
    __shared__ float redf[4][4];
    __shared__ int redi[4][3];
    __shared__ int lastFlag;
    __shared__ double redd[4][7];

    const int lx = threadIdx.x;  // 0..31
    const int ly = threadIdx.y;  // 0..7
    const int tid = ly * 32 + lx;
    const int wave = tid >> 6;
    const int lane = tid & 63;

    const int bx0 = blockIdx.x * TW;
    const int by0 = blockIdx.y * TILEH;
    const int b = blockIdx.z;
    const int blk = blockIdx.x + NBX * (blockIdx.y + NBY * blockIdx.z);

    const int* T = tgt + (size_t)b * H * W;

    // ---- build 40 edge-row bitmasks (10 rows/wave) and stash tile classes ----
    {
        const int ex = bx0 - 4 + lane;
        const bool xok = (lane < 40) & (ex >= 0) & (ex < W);
        const int r0 = wave * 10;
        int ey = by0 - 4 + r0;
        int tup = 0;
        if (xok && (ey - 1) >= 0) tup = T[(ey - 1) * W + ex];
        #pragma unroll
        for (int i = 0; i < 10; ++i, ++ey) {
            const int r = r0 + i;
            const bool rok = xok & (ey >= 0) & (ey < H);
            int t0 = rok ? T[ey * W + ex] : 0;
            int tl = __shfl_up(t0, 1, 64);
            if (lane == 0) tl = (rok & (ex > 0)) ? T[ey * W + ex - 1] : t0;
            bool e = rok & ((((ey > 0) & (t0 != tup))) | (((ex > 0) & (t0 != tl))));
            unsigned long long m = __ballot(e);
            if (lane == 0) emask[r] = m;
            if ((r >= 4) & (r < 36) & (lane >= 4) & (lane < 36))
                tileT[r - 4][lane - 4] = (unsigned char)t0;
            tup = t0;
        }
    }
    __syncthreads();

    // ---- per-thread: 1 row x 4 consecutive columns ----
    const int g = lx & 7;               // column group: cols 4g..4g+3
    const int row = ly * 4 + (lx >> 3); // tile row 0..31
    const int gy = by0 + row;
    const int gx0 = bx0 + 4 * g;
    const float* Pb = preds + (size_t)b * 3 * H * W;
    const size_t pix = (size_t)gy * W + gx0;
    const float4 q0 = *(const float4*)(Pb + pix);
    const float4 q1 = *(const float4*)(Pb + pix + (size_t)H * W);
    const float4 q2 = *(const float4*)(Pb + pix + (size_t)2 * H * W);
    const uchar4 tt = *(const uchar4*)&tileT[row][4 * g];

    unsigned long long rowm[5];
    rowm[0] = emask[row + 4];
    #pragma unroll
    for (int a = 1; a <= 4; ++a) rowm[a] = emask[row + 4 + a] | emask[row + 4 - a];

    const unsigned int allowA[5] = {0x1FFu, 0x1FFu, 0x1FFu, 0xFEu, 0x7Cu};

    float s0 = 0.f, s1 = 0.f, s2 = 0.f, s3 = 0.f;  // ce*w, p1*t1, p1, w
    int c_t1 = 0, c_bm = 0, c_ok = 0;

    #pragma unroll
    for (int c = 0; c < 4; ++c) {
        const int px = 4 * g + c;
        int d2min = 25;
        #pragma unroll
        for (int a = 0; a < 5; ++a) {
            unsigned int bb = (unsigned int)(rowm[a] >> px) & allowA[a];
            if (bb) {
                // nearest set bit to center (bit 4): fold sides, ctz
                unsigned int u = ((bb >> 4) & 31u) | (__brev(bb & 31u) >> 27);
                int ax = __ffs(u) - 1;
                d2min = min(d2min, a * a + ax * ax);
            }
        }
        float dist = (d2min >= 25) ? 5.0f : sqrtf((float)d2min);
        float wgt = (d2min >= 25) ? 1.0f : (2.0f - dist * 0.2f);

        const int t = (c == 0) ? tt.x : ((c == 1) ? tt.y : ((c == 2) ? tt.z : tt.w));
        const float p0 = (c == 0) ? q0.x : ((c == 1) ? q0.y : ((c == 2) ? q0.z : q0.w));
        const float p1 = (c == 0) ? q1.x : ((c == 1) ? q1.y : ((c == 2) ? q1.z : q1.w));
        const float p2 = (c == 0) ? q2.x : ((c == 1) ? q2.y : ((c == 2) ? q2.z : q2.w));

        float mx = fmaxf(p0, fmaxf(p1, p2));
        float e0 = __expf(p0 - mx), e1 = __expf(p1 - mx), e2 = __expf(p2 - mx);
        float se = e0 + e1 + e2;
        float lse = mx + __logf(se);
        float pt = (t == 0) ? p0 : ((t == 1) ? p1 : p2);
        float ce = lse - pt;
        float prob1 = e1 / se;

        int cls = 0;
        float best = p0;
        if (p1 > best) { best = p1; cls = 1; }
        if (p2 > best) { cls = 2; }

        bool bm = wgt > 1.5f;
        bool ok = bm & (cls == t);
        c_t1 += __popcll(__ballot(t == 1));
        c_bm += __popcll(__ballot(bm));
        c_ok += __popcll(__ballot(ok));

        s0 += ce * wgt;
        s1 += (t == 1) ? prob1 : 0.0f;
        s2 += prob1;
        s3 += wgt;
    }

    #pragma unroll
    for (int off = 32; off >= 1; off >>= 1) {
        s0 += __shfl_down(s0, off, 64);
        s1 += __shfl_down(s1, off, 64);
        s2 += __shfl_down(s2, off, 64);
        s3 += __shfl_down(s3, off, 64);
    }
    if (lane == 0) {
        redf[wave][0] = s0; redf[wave][1] = s1; redf[wave][2] = s2; redf[wave][3] = s3;
        redi[wave][0] = c_t1; redi[wave][1] = c_bm; redi[wave][2] = c_ok;
    }
    __syncthreads();
    if (tid == 0) {
        float f0 = redf[0][0] + redf[1][0] + redf[2][0] + redf[3][0];
        float f1 = redf[0][1] + redf[1][1] + redf[2][1] + redf[3][1];
        float f2 = redf[0][2] + redf[1][2] + redf[2][2] + redf[3][2];
        float f3 = redf[0][3] + redf[1][3] + redf[2][3] + redf[3][3];
        int i0 = redi[0][0] + redi[1][0] + redi[2][0] + redi[3][0];
        int i1 = redi[0][1] + redi[1][1] + redi[2][1] + redi[3][1];
        int i2 = redi[0][2] + redi[1][2] + redi[2][2] + redi[3][2];
        partials[0 * NBLK + blk] = f0;
        partials[1 * NBLK + blk] = f1;
        partials[2 * NBLK + blk] = f2;
        partials[3 * NBLK + blk] = (float)i0;
        partials[4 * NBLK + blk] = f3;
        partials[5 * NBLK + blk] = (float)i1;
        partials[6 * NBLK + blk] = (float)i2;
        __threadfence();  // release partials before signaling
        unsigned int prev = atomicAdd(counter, 1u);
        lastFlag = (prev == NBLK - 1) ? 1 : 0;
    }
    __syncthreads();
    if (!lastFlag) return;

    // ---- last block: final reduction over 7 x 2048 partials ----
    __threadfence();  // acquire: invalidate caches so partials reads are fresh
    const float4* p4 = (const float4*)partials;
    double s[7];
    #pragma unroll
    for (int k = 0; k < 7; ++k) {
        float4 va = p4[k * 512 + tid];
        float4 vb = p4[k * 512 + 256 + tid];
        s[k] = (((double)va.x + va.y) + ((double)va.z + va.w)) +
               (((double)vb.x + vb.y) + ((double)vb.z + vb.w));
    }
    #pragma unroll
    for (int off = 32; off >= 1; off >>= 1) {
        #pragma unroll
        for (int k = 0; k < 7; ++k) s[k] += __shfl_down(s[k], off, 64);
    }
    if (lane == 0) {
        #pragma unroll
        for (int k = 0; k < 7; ++k) redd[wave][k] = s[k];
    }
    __syncthreads();
    if (tid == 0) {
        double f[7];
        #pragma unroll
        for (int k = 0; k < 7; ++k)
            f[k] = redd[0][k] + redd[1][k] + redd[2][k] + redd[3][k];
        const double N = (double)B * H * W;
        double wce = f[0] / N;
        double dice = (2.0 * f[1] + 1.0) / (f[2] + f[3] + 1.0);
        double dl = 1.0 - dice;
        double bacc = (f[5] > 0.0) ? (f[6] / f[5]) : 0.0;
        double aw = f[4] / N;
        out[0] = (float)(wce + dl);
        out[1] = (float)wce;
        out[2] = (float)dl;
        out[3] = (float)bacc;
        out[4] = (float)aw;
    }
}

extern "C" void kernel_launch(void* const* d_in, const int* in_sizes, int n_in,
                              void* d_out, int out_size, void* d_ws, size_t ws_size,
                              hipStream_t stream) {
    const float* preds = (const float*)d_in[0];
    const int* tgt = (const int*)d_in[1];
    float* partials = (float*)d_ws;                                   // 7*2048*4 = 57344 B
    unsigned int* counter = (unsigned int*)((char*)d_ws + 7 * NBLK * 4);

    hipMemsetAsync(counter, 0, sizeof(unsigned int), stream);  // graph-safe stream op

    dim3 grid(NBX, NBY, B);
    dim3 block(TW, 8);
    seg_fused<<<grid, block, 0, stream>>>(preds, tgt, partials, counter, (float*)d_out);
}

// Round 4
// 24.028 us; speedup vs baseline: 3.4021x; 3.4021x over previous
//
#include <hip/hip_runtime.h>
#include <stdint.h>

#define H 512
#define W 512
#define B 8
#define TW 32
#define TILEH 32
#define NBX (W / TW)          // 16
#define NBY (H / TILEH)       // 16
#define NBLK (NBX * NBY * B)  // 2048

// seg_main: edges via wave-ballot bitmasks (40x40 halo), target tile stashed in
// LDS, clipped EDT from folded row bitmasks (branchless nearest-bit), softmax/
// CE/dice/argmax for 1 row x 4 cols per thread (float4 loads), ballot+popc for
// indicators, shuffle reduce -> 7 per-block partials. No atomics, no fences.
__global__ __launch_bounds__(256) void seg_main(const float* __restrict__ preds,
                                                const int* __restrict__ tgt,
                                                float* __restrict__ partials) {
    __shared__ unsigned long long emask[40];   // rows by0-4 .. by0+35; bit c <-> ex = bx0-4+c
    __shared__ unsigned char tileT[32][32];    // target classes of the owned tile
    __shared__ float redf[4][4];
    __shared__ int redi[4][3];

    const int lx = threadIdx.x;  // 0..31
    const int ly = threadIdx.y;  // 0..7
    const int tid = ly * 32 + lx;
    const int wave = tid >> 6;
    const int lane = tid & 63;

    const int bx0 = blockIdx.x * TW;
    const int by0 = blockIdx.y * TILEH;
    const int b = blockIdx.z;
    const int blk = blockIdx.x + NBX * (blockIdx.y + NBY * blockIdx.z);

    const int* T = tgt + (size_t)b * H * W;

    // ---- build 40 edge-row bitmasks (10 rows/wave) and stash tile classes ----
    {
        const int ex = bx0 - 4 + lane;
        const bool xok = (lane < 40) & (ex >= 0) & (ex < W);
        const int r0 = wave * 10;
        int ey = by0 - 4 + r0;
        int tup = 0;
        if (xok && (ey - 1) >= 0) tup = T[(ey - 1) * W + ex];
        #pragma unroll
        for (int i = 0; i < 10; ++i, ++ey) {
            const int r = r0 + i;
            const bool rok = xok & (ey >= 0) & (ey < H);
            int t0 = rok ? T[ey * W + ex] : 0;
            int tl = __shfl_up(t0, 1, 64);
            if (lane == 0) tl = (rok & (ex > 0)) ? T[ey * W + ex - 1] : t0;
            bool e = rok & ((((ey > 0) & (t0 != tup))) | (((ex > 0) & (t0 != tl))));
            unsigned long long m = __ballot(e);
            if (lane == 0) emask[r] = m;
            if ((r >= 4) & (r < 36) & (lane >= 4) & (lane < 36))
                tileT[r - 4][lane - 4] = (unsigned char)t0;
            tup = t0;
        }
    }
    __syncthreads();

    // ---- per-thread: 1 row x 4 consecutive columns ----
    const int g = lx & 7;               // column group: cols 4g..4g+3
    const int row = ly * 4 + (lx >> 3); // tile row 0..31
    const int gy = by0 + row;
    const int gx0 = bx0 + 4 * g;
    const float* Pb = preds + (size_t)b * 3 * H * W;
    const size_t pix = (size_t)gy * W + gx0;
    const float4 q0 = *(const float4*)(Pb + pix);
    const float4 q1 = *(const float4*)(Pb + pix + (size_t)H * W);
    const float4 q2 = *(const float4*)(Pb + pix + (size_t)2 * H * W);
    const uchar4 tt = *(const uchar4*)&tileT[row][4 * g];

    unsigned long long rowm[5];
    rowm[0] = emask[row + 4];
    #pragma unroll
    for (int a = 1; a <= 4; ++a) rowm[a] = emask[row + 4 + a] | emask[row + 4 - a];

    const unsigned int allowA[5] = {0x1FFu, 0x1FFu, 0x1FFu, 0xFEu, 0x7Cu};

    float s0 = 0.f, s1 = 0.f, s2 = 0.f, s3 = 0.f;  // ce*w, p1*t1, p1, w
    int c_t1 = 0, c_bm = 0, c_ok = 0;

    #pragma unroll
    for (int c = 0; c < 4; ++c) {
        const int px = 4 * g + c;
        int d2min = 25;
        #pragma unroll
        for (int a = 0; a < 5; ++a) {
            unsigned int bb = (unsigned int)(rowm[a] >> px) & allowA[a];
            // nearest set bit to center (bit 4): fold sides, ctz; empty -> ax=5
            unsigned int u = ((bb >> 4) & 31u) | (__brev(bb & 31u) >> 27) | 0x20u;
            int ax = __ffs(u) - 1;
            d2min = min(d2min, a * a + ax * ax);
        }
        float dist = (d2min >= 25) ? 5.0f : sqrtf((float)d2min);
        float wgt = (d2min >= 25) ? 1.0f : (2.0f - dist * 0.2f);

        const int t = (c == 0) ? tt.x : ((c == 1) ? tt.y : ((c == 2) ? tt.z : tt.w));
        const float p0 = (c == 0) ? q0.x : ((c == 1) ? q0.y : ((c == 2) ? q0.z : q0.w));
        const float p1 = (c == 0) ? q1.x : ((c == 1) ? q1.y : ((c == 2) ? q1.z : q1.w));
        const float p2 = (c == 0) ? q2.x : ((c == 1) ? q2.y : ((c == 2) ? q2.z : q2.w));

        float mx = fmaxf(p0, fmaxf(p1, p2));
        float e0 = __expf(p0 - mx), e1 = __expf(p1 - mx), e2 = __expf(p2 - mx);
        float se = e0 + e1 + e2;
        float lse = mx + __logf(se);
        float pt = (t == 0) ? p0 : ((t == 1) ? p1 : p2);
        float ce = lse - pt;
        float prob1 = e1 / se;

        int cls = 0;
        float best = p0;
        if (p1 > best) { best = p1; cls = 1; }
        if (p2 > best) { cls = 2; }

        bool bm = wgt > 1.5f;
        bool ok = bm & (cls == t);
        c_t1 += __popcll(__ballot(t == 1));
        c_bm += __popcll(__ballot(bm));
        c_ok += __popcll(__ballot(ok));

        s0 += ce * wgt;
        s1 += (t == 1) ? prob1 : 0.0f;
        s2 += prob1;
        s3 += wgt;
    }

    #pragma unroll
    for (int off = 32; off >= 1; off >>= 1) {
        s0 += __shfl_down(s0, off, 64);
        s1 += __shfl_down(s1, off, 64);
        s2 += __shfl_down(s2, off, 64);
        s3 += __shfl_down(s3, off, 64);
    }
    if (lane == 0) {
        redf[wave][0] = s0; redf[wave][1] = s1; redf[wave][2] = s2; redf[wave][3] = s3;
        redi[wave][0] = c_t1; redi[wave][1] = c_bm; redi[wave][2] = c_ok;
    }
    __syncthreads();
    if (tid == 0) {
        float f0 = redf[0][0] + redf[1][0] + redf[2][0] + redf[3][0];
        float f1 = redf[0][1] + redf[1][1] + redf[2][1] + redf[3][1];
        float f2 = redf[0][2] + redf[1][2] + redf[2][2] + redf[3][2];
        float f3 = redf[0][3] + redf[1][3] + redf[2][3] + redf[3][3];
        int i0 = redi[0][0] + redi[1][0] + redi[2][0] + redi[3][0];
        int i1 = redi[0][1] + redi[1][1] + redi[2][1] + redi[3][1];
        int i2 = redi[0][2] + redi[1][2] + redi[2][2] + redi[3][2];
        partials[0 * NBLK + blk] = f0;          // sum ce*w
        partials[1 * NBLK + blk] = f1;          // sum p1*t1
        partials[2 * NBLK + blk] = f2;          // sum p1
        partials[3 * NBLK + blk] = (float)i0;   // sum t1
        partials[4 * NBLK + blk] = f3;          // sum w
        partials[5 * NBLK + blk] = (float)i1;   // cnt
        partials[6 * NBLK + blk] = (float)i2;   // correct
    }
}

__global__ __launch_bounds__(256) void seg_final(const float* __restrict__ partials,
                                                 float* __restrict__ out) {
    __shared__ double red[4][7];
    const int tid = threadIdx.x;
    const int wave = tid >> 6, lane = tid & 63;

    // 2048 floats per quantity = 512 float4; 256 threads x 2 float4 each.
    const float4* p4 = (const float4*)partials;
    float4 va[7], vb[7];
    #pragma unroll
    for (int k = 0; k < 7; ++k) {
        va[k] = p4[k * 512 + tid];
        vb[k] = p4[k * 512 + 256 + tid];
    }
    double s[7];
    #pragma unroll
    for (int k = 0; k < 7; ++k)
        s[k] = (((double)va[k].x + va[k].y) + ((double)va[k].z + va[k].w)) +
               (((double)vb[k].x + vb[k].y) + ((double)vb[k].z + vb[k].w));

    #pragma unroll
    for (int off = 32; off >= 1; off >>= 1) {
        #pragma unroll
        for (int k = 0; k < 7; ++k) s[k] += __shfl_down(s[k], off, 64);
    }
    if (lane == 0) {
        #pragma unroll
        for (int k = 0; k < 7; ++k) red[wave][k] = s[k];
    }
    __syncthreads();
    if (tid == 0) {
        double f[7];
        #pragma unroll
        for (int k = 0; k < 7; ++k)
            f[k] = red[0][k] + red[1][k] + red[2][k] + red[3][k];
        const double N = (double)B * H * W;
        double wce = f[0] / N;
        double dice = (2.0 * f[1] + 1.0) / (f[2] + f[3] + 1.0);
        double dl = 1.0 - dice;
        double bacc = (f[5] > 0.0) ? (f[6] / f[5]) : 0.0;
        double aw = f[4] / N;
        out[0] = (float)(wce + dl);
        out[1] = (float)wce;
        out[2] = (float)dl;
        out[3] = (float)bacc;
        out[4] = (float)aw;
    }
}

extern "C" void kernel_launch(void* const* d_in, const int* in_sizes, int n_in,
                              void* d_out, int out_size, void* d_ws, size_t ws_size,
                              hipStream_t stream) {
    const float* preds = (const float*)d_in[0];
    const int* tgt = (const int*)d_in[1];
    float* partials = (float*)d_ws;  // needs 7 * 2048 * 4 = 57,344 bytes

    dim3 grid(NBX, NBY, B);
    dim3 block(TW, 8);
    seg_main<<<grid, block, 0, stream>>>(preds, tgt, partials);
    seg_final<<<1, 256, 0, stream>>>(partials, (float*)d_out);
}